// Round 5
// baseline (699.083 us; speedup 1.0000x reference)
//
#include <hip/hip_runtime.h>
#include <hip/hip_bf16.h>
#include <cstdint>
#include <cstddef>

#define NN 50000
#define NE 800000

typedef __bf16 bf16x8 __attribute__((ext_vector_type(8)));
typedef float  f32x4  __attribute__((ext_vector_type(4)));

// Pre-split, pre-transposed weights (hi/lo bf16 planes).
// W1t: [n][k] n<64,k<256 ; W2t: [n][k] n<128,k<64 ; Wd1t: [n][k] n<64,k<128.
__device__ __bf16 g_w1h[2][64 * 256];
__device__ __bf16 g_w1l[2][64 * 256];
__device__ __bf16 g_w2h[2][128 * 64];
__device__ __bf16 g_w2l[2][128 * 64];
__device__ __bf16 g_wd1h[64 * 128];
__device__ __bf16 g_wd1l[64 * 128];

__device__ __forceinline__ void split1(float v, __bf16& h, __bf16& l) {
    h = (__bf16)v;
    l = (__bf16)(v - (float)h);
}

// ---------------------------------------------------------------------------
// pre_kernel: blocks [0,224) split weights; blocks [224,224+3125) histogram
// ---------------------------------------------------------------------------
__global__ __launch_bounds__(256) void pre_kernel(
    const float* __restrict__ W1a, const float* __restrict__ W2a,
    const float* __restrict__ W1b, const float* __restrict__ W2b,
    const float* __restrict__ Wd1,
    const int* __restrict__ rcv, uint32_t* __restrict__ hist)
{
    const int b = blockIdx.x, t = threadIdx.x;
    if (b < 224) {
        int tid = b * 256 + t;
        if (tid < 16384) {                 // W1a [256][64] -> [64][256]
            int k = tid >> 6, n = tid & 63;
            __bf16 h, l; split1(W1a[tid], h, l);
            g_w1h[0][n * 256 + k] = h; g_w1l[0][n * 256 + k] = l;
        } else if (tid < 24576) {          // W2a [64][128] -> [128][64]
            int i = tid - 16384; int k = i >> 7, n = i & 127;
            __bf16 h, l; split1(W2a[i], h, l);
            g_w2h[0][n * 64 + k] = h; g_w2l[0][n * 64 + k] = l;
        } else if (tid < 40960) {          // W1b
            int i = tid - 24576; int k = i >> 6, n = i & 63;
            __bf16 h, l; split1(W1b[i], h, l);
            g_w1h[1][n * 256 + k] = h; g_w1l[1][n * 256 + k] = l;
        } else if (tid < 49152) {          // W2b
            int i = tid - 40960; int k = i >> 7, n = i & 127;
            __bf16 h, l; split1(W2b[i], h, l);
            g_w2h[1][n * 64 + k] = h; g_w2l[1][n * 64 + k] = l;
        } else if (tid < 57344) {          // Wd1 [128][64] -> [64][128]
            int i = tid - 49152; int k = i >> 6, n = i & 63;
            __bf16 h, l; split1(Wd1[i], h, l);
            g_wd1h[n * 128 + k] = h; g_wd1l[n * 128 + k] = l;
        }
    } else {
        int e = (b - 224) * 256 + t;
        if (e < NE) atomicAdd(hist + rcv[e], 1u);
    }
}

// ---------------------------------------------------------------------------
// counting-sort scan (exact counts)
// ---------------------------------------------------------------------------
__global__ void scan1_kernel(const uint32_t* __restrict__ hist,
                             uint32_t* __restrict__ pre, uint32_t* __restrict__ bsum) {
    __shared__ uint32_t s[256];
    int t = threadIdx.x;
    int i = blockIdx.x * 256 + t;
    uint32_t v = (i < NN) ? hist[i] : 0u;
    s[t] = v; __syncthreads();
    #pragma unroll
    for (int off = 1; off < 256; off <<= 1) {
        uint32_t tv = (t >= off) ? s[t - off] : 0u;
        __syncthreads();
        s[t] += tv; __syncthreads();
    }
    if (i < NN) pre[i] = s[t] - v;
    if (t == 255) bsum[blockIdx.x] = s[255];
}

__global__ void scan23_kernel(const uint32_t* __restrict__ pre,
                              const uint32_t* __restrict__ bsum,
                              uint32_t* __restrict__ row_off) {
    __shared__ uint32_t s[256];
    const int b = blockIdx.x, t = threadIdx.x;
    uint32_t v = (t < b) ? bsum[t] : 0u;     // b <= 195 < 256
    s[t] = v; __syncthreads();
    #pragma unroll
    for (int off = 128; off > 0; off >>= 1) {
        if (t < off) s[t] += s[t + off];
        __syncthreads();
    }
    const uint32_t base = s[0];
    int i = b * 256 + t;
    if (i < NN) row_off[i] = pre[i] + base;
    if (i == 0) row_off[NN] = NE;
}

// ---------------------------------------------------------------------------
// node_w1_body: layer-0 per-node half-products of GEMM1 (global src).
//   hrp[n] = src[n] @ W1_top + b1 ; hsp[n] = src[n] @ W1_bot
// ---------------------------------------------------------------------------
__device__ __forceinline__ void node_w1_body(
    const float* __restrict__ src, const float* __restrict__ b1,
    float* __restrict__ hrp, float* __restrict__ hsp, int blk)
{
    __shared__ __align__(16) __bf16 sAh[64 * 136];
    __shared__ __align__(16) __bf16 sAl[64 * 136];
    const int t = threadIdx.x;
    const int w = t >> 6, lane = t & 63, quad = lane >> 4, l16 = lane & 15;
    const int node0 = blk * 64;

    {
        const int r = t >> 2, kq = (t & 3) * 32;
        const int node = node0 + r;
        f32x4 v[8];
        if (node < NN) {
            const float* p = src + (size_t)node * 128 + kq;
            #pragma unroll
            for (int i = 0; i < 8; ++i) v[i] = *(const f32x4*)(p + 4 * i);
        } else {
            #pragma unroll
            for (int i = 0; i < 8; ++i) v[i] = (f32x4){0.f, 0.f, 0.f, 0.f};
        }
        bf16x8 hb[4], lb[4];
        #pragma unroll
        for (int i = 0; i < 8; ++i) {
            #pragma unroll
            for (int j = 0; j < 4; ++j) {
                __bf16 h, l; split1(v[i][j], h, l);
                hb[i >> 1][(i & 1) * 4 + j] = h;
                lb[i >> 1][(i & 1) * 4 + j] = l;
            }
        }
        __bf16* dh = sAh + r * 136 + kq;
        __bf16* dl = sAl + r * 136 + kq;
        #pragma unroll
        for (int i = 0; i < 4; ++i) {
            *(bf16x8*)(dh + 8 * i) = hb[i];
            *(bf16x8*)(dl + 8 * i) = lb[i];
        }
    }
    __syncthreads();

    const int n = 16 * w + l16;
    const __bf16* w1hp = g_w1h[0] + n * 256;
    const __bf16* w1lp = g_w1l[0] + n * 256;
    f32x4 acc[4][2] = {};
    #pragma unroll
    for (int kq = 0; kq < 4; ++kq) {
        const int k0 = kq * 32 + quad * 8;
        bf16x8 bh0 = *(const bf16x8*)(w1hp + k0);
        bf16x8 bl0 = *(const bf16x8*)(w1lp + k0);
        bf16x8 bh1 = *(const bf16x8*)(w1hp + 128 + k0);
        bf16x8 bl1 = *(const bf16x8*)(w1lp + 128 + k0);
        #pragma unroll
        for (int st = 0; st < 4; ++st) {
            bf16x8 ah = *(const bf16x8*)(sAh + (16 * st + l16) * 136 + k0);
            bf16x8 al = *(const bf16x8*)(sAl + (16 * st + l16) * 136 + k0);
            acc[st][0] = __builtin_amdgcn_mfma_f32_16x16x32_bf16(ah, bh0, acc[st][0], 0, 0, 0);
            acc[st][0] = __builtin_amdgcn_mfma_f32_16x16x32_bf16(al, bh0, acc[st][0], 0, 0, 0);
            acc[st][0] = __builtin_amdgcn_mfma_f32_16x16x32_bf16(ah, bl0, acc[st][0], 0, 0, 0);
            acc[st][1] = __builtin_amdgcn_mfma_f32_16x16x32_bf16(ah, bh1, acc[st][1], 0, 0, 0);
            acc[st][1] = __builtin_amdgcn_mfma_f32_16x16x32_bf16(al, bh1, acc[st][1], 0, 0, 0);
            acc[st][1] = __builtin_amdgcn_mfma_f32_16x16x32_bf16(ah, bl1, acc[st][1], 0, 0, 0);
        }
    }

    const float b1v = b1[n];
    #pragma unroll
    for (int st = 0; st < 4; ++st) {
        #pragma unroll
        for (int r = 0; r < 4; ++r) {
            const int node = node0 + 16 * st + quad * 4 + r;
            if (node < NN) {
                hrp[(size_t)node * 64 + n] = acc[st][0][r] + b1v;
                hsp[(size_t)node * 64 + n] = acc[st][1][r];
            }
        }
    }
}

// ---------------------------------------------------------------------------
// mid_kernel: blocks [0,nbn) = node_w1 layer-0; rest = rank-scatter.
// ---------------------------------------------------------------------------
__global__ __launch_bounds__(256) void mid_kernel(
    const float* __restrict__ x, const float* __restrict__ b1a,
    float* __restrict__ hrp, float* __restrict__ hsp,
    const int* __restrict__ rcv, const int* __restrict__ snd,
    const uint32_t* __restrict__ row_off, uint32_t* __restrict__ cursor,
    int2* __restrict__ srt, int nbn)
{
    if ((int)blockIdx.x < nbn) {
        node_w1_body(x, b1a, hrp, hsp, blockIdx.x);
    } else {
        int e = (blockIdx.x - nbn) * 256 + threadIdx.x;
        if (e < NE) {
            int r = rcv[e];
            uint32_t k = atomicAdd(cursor + r, 1u);
            srt[row_off[r] + k] = make_int2(r, snd[e]);
        }
    }
}

// ---------------------------------------------------------------------------
// fused_edge_kernel v2: NODE-CENTRIC, 512 threads (8 waves).
// Block owns 64 receivers and their sorted edge range. Segment sums in a
// 64(+1 dump)x128 f32 LDS accumulator -> zero global atomics.
// Branch-free suffix-sum epilogue: per strip precompute run-continuation
// coeffs c01/c12/c23 + head flags; per ct: t_p = v_p + c*t_{p+1}, then <=4
// predicated ds_adds (slot0 ~always, slots1-3 ~6%). No cross-lane shuffles
// or branchy merges in the hot loop (round-4's stall source).
// __launch_bounds__(512,4) caps VGPR at 128 so 2 blocks (16 waves)/CU fit.
// Then fused per block: mean via hist, and
//   tail_mode=0: layer-2 GEMM1 -> hrpO/hspO   tail_mode=1: dense tail -> outp
// GEMM phase uses all 8 waves: waves 0-3 node-strips {0,1}, waves 4-7 {2,3}.
// ---------------------------------------------------------------------------
__global__ __launch_bounds__(512, 4) void fused_edge_kernel(
    const float* __restrict__ hrpI, const float* __restrict__ hspI,
    const int2* __restrict__ srt, const uint32_t* __restrict__ row_off,
    const uint32_t* __restrict__ hist,
    const float* __restrict__ b2, int layer,
    const float* __restrict__ b1n, float* __restrict__ hrpO, float* __restrict__ hspO,
    const float* __restrict__ bd1, const float* __restrict__ Wd2,
    const float* __restrict__ bd2, float* __restrict__ outp,
    int tail_mode)
{
    __shared__ __align__(16) float sAcc[65][128];              // 33280 B (row 64 = dump)
    __shared__ __align__(16) char  sBuf[64 * 136 * 2 * 2];     // 34816 B
    __shared__ float sOut[64];

    __bf16* sWh = (__bf16*)sBuf;            // [128*64] during edge phase
    __bf16* sWl = sWh + 128 * 64;
    __bf16* sAh = (__bf16*)sBuf;            // [64*136] during GEMM phase
    __bf16* sAl = sAh + 64 * 136;

    const int t = threadIdx.x;
    const int w = t >> 6, lane = t & 63, quad = lane >> 4, l16 = lane & 15;
    const int node0 = blockIdx.x * 64;

    // ---- zero sAcc (8320 f32 / 512 threads) --------------------------------
    #pragma unroll
    for (int i = 0; i < 4; ++i)
        *(f32x4*)(&sAcc[0][0] + t * 4 + i * 2048) = (f32x4){0.f, 0.f, 0.f, 0.f};
    if (t < 128) sAcc[64][t] = 0.f;
    if (t < 64) sOut[t] = 0.f;

    // ---- stage W2 planes, swizzled (chunk c of row r at slot c^(r&7)) ------
    {
        const int r = t >> 2, part = t & 3;
        const __bf16* sh = g_w2h[layer] + r * 64;
        const __bf16* sl = g_w2l[layer] + r * 64;
        __bf16* dh = sWh + r * 64;
        __bf16* dl = sWl + r * 64;
        const int rs = r & 7;
        #pragma unroll
        for (int i = 0; i < 2; ++i) {
            const int c = part * 2 + i;
            const int cs = c ^ rs;
            *(bf16x8*)(dh + cs * 8) = *(const bf16x8*)(sh + 8 * c);
            *(bf16x8*)(dl + cs * 8) = *(const bf16x8*)(sl + 8 * c);
        }
    }

    float b2v[8];
    #pragma unroll
    for (int ct = 0; ct < 8; ++ct) b2v[ct] = b2[16 * ct + l16];

    const int e0 = (int)row_off[node0];
    const int e1 = (int)row_off[(node0 + 64 < NN) ? (node0 + 64) : NN];

    __syncthreads();   // sAcc zeroed + weights staged

    // ---- edge loop: wave w handles 32 edges/iter, 8 waves stride 256 -------
    for (int base = e0 + w * 32; base < e1; base += 256) {
        const int iA = base + l16;
        const int iB = base + 16 + l16;
        const bool vA = iA < e1;
        const bool vB = iB < e1;
        const int2 rsA = srt[vA ? iA : e1 - 1];
        const int2 rsB = srt[vB ? iB : e1 - 1];
        const int rlA = vA ? (rsA.x - node0) : -1;   // local receiver or -1
        const int rlB = vB ? (rsB.x - node0) : -1;

        const float* hpA = hrpI + (size_t)rsA.x * 64 + quad * 8;
        const float* spA = hspI + (size_t)rsA.y * 64 + quad * 8;
        const float* hpB = hrpI + (size_t)rsB.x * 64 + quad * 8;
        const float* spB = hspI + (size_t)rsB.y * 64 + quad * 8;

        f32x4 ga0[4], gb0[4], ga1[4], gb1[4];
        ga0[0] = *(const f32x4*)(hpA);      ga0[1] = *(const f32x4*)(hpA + 4);
        ga0[2] = *(const f32x4*)(hpA + 32); ga0[3] = *(const f32x4*)(hpA + 36);
        gb0[0] = *(const f32x4*)(spA);      gb0[1] = *(const f32x4*)(spA + 4);
        gb0[2] = *(const f32x4*)(spA + 32); gb0[3] = *(const f32x4*)(spA + 36);
        ga1[0] = *(const f32x4*)(hpB);      ga1[1] = *(const f32x4*)(hpB + 4);
        ga1[2] = *(const f32x4*)(hpB + 32); ga1[3] = *(const f32x4*)(hpB + 36);
        gb1[0] = *(const f32x4*)(spB);      gb1[1] = *(const f32x4*)(spB + 4);
        gb1[2] = *(const f32x4*)(spB + 32); gb1[3] = *(const f32x4*)(spB + 36);

        // ---- per-quad receivers + branch-free run structure (per strip) ----
        const int rA0 = __shfl(rlA, quad * 4 + 0, 16);
        const int rA1 = __shfl(rlA, quad * 4 + 1, 16);
        const int rA2 = __shfl(rlA, quad * 4 + 2, 16);
        const int rA3 = __shfl(rlA, quad * 4 + 3, 16);
        const int rB0 = __shfl(rlB, quad * 4 + 0, 16);
        const int rB1 = __shfl(rlB, quad * 4 + 1, 16);
        const int rB2 = __shfl(rlB, quad * 4 + 2, 16);
        const int rB3 = __shfl(rlB, quad * 4 + 3, 16);

        const float cA01 = (rA1 == rA0) ? 1.f : 0.f;
        const float cA12 = (rA2 == rA1) ? 1.f : 0.f;
        const float cA23 = (rA3 == rA2) ? 1.f : 0.f;
        const bool hA0 = (rA0 >= 0);
        const bool hA1 = (rA1 != rA0) && (rA1 >= 0);
        const bool hA2 = (rA2 != rA1) && (rA2 >= 0);
        const bool hA3 = (rA3 != rA2) && (rA3 >= 0);
        const float mA0 = (rA0 >= 0) ? 1.f : 0.f;
        const float mA1 = (rA1 >= 0) ? 1.f : 0.f;
        const float mA2 = (rA2 >= 0) ? 1.f : 0.f;
        const float mA3 = (rA3 >= 0) ? 1.f : 0.f;

        const float cB01 = (rB1 == rB0) ? 1.f : 0.f;
        const float cB12 = (rB2 == rB1) ? 1.f : 0.f;
        const float cB23 = (rB3 == rB2) ? 1.f : 0.f;
        const bool hB0 = (rB0 >= 0);
        const bool hB1 = (rB1 != rB0) && (rB1 >= 0);
        const bool hB2 = (rB2 != rB1) && (rB2 >= 0);
        const bool hB3 = (rB3 != rB2) && (rB3 >= 0);
        const float mB0 = (rB0 >= 0) ? 1.f : 0.f;
        const float mB1 = (rB1 >= 0) ? 1.f : 0.f;
        const float mB2 = (rB2 >= 0) ? 1.f : 0.f;
        const float mB3 = (rB3 >= 0) ? 1.f : 0.f;

        // ---- pack A-fragments: h = relu(hrp+hsp), split hi/lo --------------
        bf16x8 ahA[2], alA[2], ahB[2], alB[2];
        #pragma unroll
        for (int s = 0; s < 2; ++s) {
            #pragma unroll
            for (int hh = 0; hh < 2; ++hh) {
                f32x4 av = ga0[s * 2 + hh], bv = gb0[s * 2 + hh];
                f32x4 aw = ga1[s * 2 + hh], bw = gb1[s * 2 + hh];
                #pragma unroll
                for (int j = 0; j < 4; ++j) {
                    float fA = fmaxf(av[j] + bv[j], 0.f);
                    float fB = fmaxf(aw[j] + bw[j], 0.f);
                    __bf16 h, l;
                    split1(fA, h, l); ahA[s][hh * 4 + j] = h; alA[s][hh * 4 + j] = l;
                    split1(fB, h, l); ahB[s][hh * 4 + j] = h; alB[s][hh * 4 + j] = l;
                }
            }
        }

        #pragma unroll
        for (int ct = 0; ct < 8; ++ct) {
            const int r = 16 * ct + l16;
            const int rs = r & 7;
            f32x4 accA = {}, accB = {};
            __builtin_amdgcn_s_setprio(1);
            #pragma unroll
            for (int s = 0; s < 2; ++s) {
                const int cs = (s * 4 + quad) ^ rs;
                bf16x8 bh = *(const bf16x8*)(sWh + r * 64 + cs * 8);
                bf16x8 bl = *(const bf16x8*)(sWl + r * 64 + cs * 8);
                accA = __builtin_amdgcn_mfma_f32_16x16x32_bf16(ahA[s], bh, accA, 0, 0, 0);
                accA = __builtin_amdgcn_mfma_f32_16x16x32_bf16(alA[s], bh, accA, 0, 0, 0);
                accA = __builtin_amdgcn_mfma_f32_16x16x32_bf16(ahA[s], bl, accA, 0, 0, 0);
                accB = __builtin_amdgcn_mfma_f32_16x16x32_bf16(ahB[s], bh, accB, 0, 0, 0);
                accB = __builtin_amdgcn_mfma_f32_16x16x32_bf16(alB[s], bh, accB, 0, 0, 0);
                accB = __builtin_amdgcn_mfma_f32_16x16x32_bf16(ahB[s], bl, accB, 0, 0, 0);
            }
            __builtin_amdgcn_s_setprio(0);
            const float bv = b2v[ct];
            // strip A: suffix-sum chain + predicated LDS atomics
            {
                const float v0 = fmaxf(accA[0] + bv, 0.f) * mA0;
                const float v1 = fmaxf(accA[1] + bv, 0.f) * mA1;
                const float v2 = fmaxf(accA[2] + bv, 0.f) * mA2;
                const float v3 = fmaxf(accA[3] + bv, 0.f) * mA3;
                const float t3 = v3;
                const float t2 = fmaf(cA23, t3, v2);
                const float t1 = fmaf(cA12, t2, v1);
                const float t0 = fmaf(cA01, t1, v0);
                if (hA0) atomicAdd(&sAcc[rA0][r], t0);
                if (hA1) atomicAdd(&sAcc[rA1][r], t1);
                if (hA2) atomicAdd(&sAcc[rA2][r], t2);
                if (hA3) atomicAdd(&sAcc[rA3][r], t3);
            }
            // strip B
            {
                const float v0 = fmaxf(accB[0] + bv, 0.f) * mB0;
                const float v1 = fmaxf(accB[1] + bv, 0.f) * mB1;
                const float v2 = fmaxf(accB[2] + bv, 0.f) * mB2;
                const float v3 = fmaxf(accB[3] + bv, 0.f) * mB3;
                const float t3 = v3;
                const float t2 = fmaf(cB23, t3, v2);
                const float t1 = fmaf(cB12, t2, v1);
                const float t0 = fmaf(cB01, t1, v0);
                if (hB0) atomicAdd(&sAcc[rB0][r], t0);
                if (hB1) atomicAdd(&sAcc[rB1][r], t1);
                if (hB2) atomicAdd(&sAcc[rB2][r], t2);
                if (hB3) atomicAdd(&sAcc[rB3][r], t3);
            }
        }
    }

    __syncthreads();   // sAcc complete; sWh/sWl dead -> reuse as sAh/sAl

    // ---- stage mean(sAcc) -> sAh/sAl (512 threads: 16 f32 each) ------------
    {
        const int r = t >> 3, kq = (t & 7) * 16;
        const int node = node0 + r;
        float inv = 0.f;
        if (node < NN) {
            const uint32_t c = hist[node];
            inv = (c > 0u) ? 1.0f / (float)c : 0.f;
        }
        f32x4 v[4];
        #pragma unroll
        for (int i = 0; i < 4; ++i)
            v[i] = *(const f32x4*)(&sAcc[r][kq + 4 * i]) * inv;
        bf16x8 hb[2], lb[2];
        #pragma unroll
        for (int i = 0; i < 4; ++i) {
            #pragma unroll
            for (int j = 0; j < 4; ++j) {
                __bf16 h, l; split1(v[i][j], h, l);
                hb[i >> 1][(i & 1) * 4 + j] = h;
                lb[i >> 1][(i & 1) * 4 + j] = l;
            }
        }
        __bf16* dh = sAh + r * 136 + kq;
        __bf16* dl = sAl + r * 136 + kq;
        *(bf16x8*)(dh) = hb[0];  *(bf16x8*)(dh + 8) = hb[1];
        *(bf16x8*)(dl) = lb[0];  *(bf16x8*)(dl + 8) = lb[1];
    }
    __syncthreads();

    // ---- GEMM phase: all 8 waves. wave w: cols 16*(w&3)+l16, strips sb,sb+1
    const int wh = w & 3;
    const int sb = (w >> 2) * 2;
    const int n = 16 * wh + l16;

    if (!tail_mode) {
        const __bf16* w1hp = g_w1h[1] + n * 256;
        const __bf16* w1lp = g_w1l[1] + n * 256;
        f32x4 acc[2][2] = {};
        #pragma unroll
        for (int kq = 0; kq < 4; ++kq) {
            const int k0 = kq * 32 + quad * 8;
            bf16x8 bh0 = *(const bf16x8*)(w1hp + k0);
            bf16x8 bl0 = *(const bf16x8*)(w1lp + k0);
            bf16x8 bh1 = *(const bf16x8*)(w1hp + 128 + k0);
            bf16x8 bl1 = *(const bf16x8*)(w1lp + 128 + k0);
            #pragma unroll
            for (int sl = 0; sl < 2; ++sl) {
                const int st = sb + sl;
                bf16x8 ah = *(const bf16x8*)(sAh + (16 * st + l16) * 136 + k0);
                bf16x8 al = *(const bf16x8*)(sAl + (16 * st + l16) * 136 + k0);
                acc[sl][0] = __builtin_amdgcn_mfma_f32_16x16x32_bf16(ah, bh0, acc[sl][0], 0, 0, 0);
                acc[sl][0] = __builtin_amdgcn_mfma_f32_16x16x32_bf16(al, bh0, acc[sl][0], 0, 0, 0);
                acc[sl][0] = __builtin_amdgcn_mfma_f32_16x16x32_bf16(ah, bl0, acc[sl][0], 0, 0, 0);
                acc[sl][1] = __builtin_amdgcn_mfma_f32_16x16x32_bf16(ah, bh1, acc[sl][1], 0, 0, 0);
                acc[sl][1] = __builtin_amdgcn_mfma_f32_16x16x32_bf16(al, bh1, acc[sl][1], 0, 0, 0);
                acc[sl][1] = __builtin_amdgcn_mfma_f32_16x16x32_bf16(ah, bl1, acc[sl][1], 0, 0, 0);
            }
        }
        const float b1v = b1n[n];
        #pragma unroll
        for (int sl = 0; sl < 2; ++sl) {
            const int st = sb + sl;
            #pragma unroll
            for (int r2 = 0; r2 < 4; ++r2) {
                const int node = node0 + 16 * st + quad * 4 + r2;
                if (node < NN) {
                    hrpO[(size_t)node * 64 + n] = acc[sl][0][r2] + b1v;
                    hspO[(size_t)node * 64 + n] = acc[sl][1][r2];
                }
            }
        }
    } else {
        const __bf16* bhp = g_wd1h + n * 128;
        const __bf16* blp = g_wd1l + n * 128;
        f32x4 acc[2] = {};
        #pragma unroll
        for (int kq = 0; kq < 4; ++kq) {
            const int k0 = kq * 32 + quad * 8;
            bf16x8 bh = *(const bf16x8*)(bhp + k0);
            bf16x8 bl = *(const bf16x8*)(blp + k0);
            #pragma unroll
            for (int sl = 0; sl < 2; ++sl) {
                const int st = sb + sl;
                bf16x8 ah = *(const bf16x8*)(sAh + (16 * st + l16) * 136 + k0);
                bf16x8 al = *(const bf16x8*)(sAl + (16 * st + l16) * 136 + k0);
                acc[sl] = __builtin_amdgcn_mfma_f32_16x16x32_bf16(ah, bh, acc[sl], 0, 0, 0);
                acc[sl] = __builtin_amdgcn_mfma_f32_16x16x32_bf16(al, bh, acc[sl], 0, 0, 0);
                acc[sl] = __builtin_amdgcn_mfma_f32_16x16x32_bf16(ah, bl, acc[sl], 0, 0, 0);
            }
        }
        const float bd1v = bd1[n];
        const float wd2v = Wd2[n];
        #pragma unroll
        for (int sl = 0; sl < 2; ++sl) {
            const int st = sb + sl;
            #pragma unroll
            for (int r2 = 0; r2 < 4; ++r2) {
                float p = fmaxf(acc[sl][r2] + bd1v, 0.f) * wd2v;
                p += __shfl_xor(p, 1, 16);
                p += __shfl_xor(p, 2, 16);
                p += __shfl_xor(p, 4, 16);
                p += __shfl_xor(p, 8, 16);
                if (l16 == 0) atomicAdd(&sOut[16 * st + quad * 4 + r2], p);
            }
        }
        __syncthreads();
        if (t < 64) {
            const int node = node0 + t;
            if (node < NN) outp[node] = sOut[t] + bd2[0];
        }
    }
}

// ---------------------------------------------------------------------------
extern "C" void kernel_launch(void* const* d_in, const int* in_sizes, int n_in,
                              void* d_out, int out_size, void* d_ws, size_t ws_size,
                              hipStream_t stream) {
    const float* x   = (const float*)d_in[0];
    const int*   snd = (const int*)  d_in[1];
    const int*   rcv = (const int*)  d_in[2];
    const float* W1a = (const float*)d_in[3];
    const float* b1a = (const float*)d_in[4];
    const float* W2a = (const float*)d_in[5];
    const float* b2a = (const float*)d_in[6];
    const float* W1b = (const float*)d_in[7];
    const float* b1b = (const float*)d_in[8];
    const float* W2b = (const float*)d_in[9];
    const float* b2b = (const float*)d_in[10];
    const float* Wd1 = (const float*)d_in[11];
    const float* bd1 = (const float*)d_in[12];
    const float* Wd2 = (const float*)d_in[13];
    const float* bd2 = (const float*)d_in[14];
    float* out = (float*)d_out;

    // ws layout: hist [NN] | cursor [NN] | row_off [NN+1] | pre [NN] |
    //            bsum [256] | pad [1] | srt [NE int2] | hrp | hsp | hrp2 | hsp2
    uint32_t* hist    = (uint32_t*)d_ws;
    uint32_t* cursor  = hist + NN;
    uint32_t* row_off = cursor + NN;
    uint32_t* pre     = row_off + (NN + 1);
    uint32_t* bsum    = pre + NN;
    int2*     srt     = (int2*)(bsum + 256 + 1);   // +1 pad -> 8B aligned
    float*    hrp     = (float*)(srt + NE);
    float*    hsp     = hrp  + (size_t)NN * 64;
    float*    hrp2    = hsp  + (size_t)NN * 64;
    float*    hsp2    = hrp2 + (size_t)NN * 64;

    hipMemsetAsync(hist, 0, 2 * NN * sizeof(uint32_t), stream);   // hist+cursor

    const int nb  = (NN + 255) / 256;   // 196
    const int nbn = (NN + 63) / 64;     // 782
    const int neb = (NE + 255) / 256;   // 3125

    hipLaunchKernelGGL(pre_kernel, dim3(224 + neb), dim3(256), 0, stream,
                       W1a, W2a, W1b, W2b, Wd1, rcv, hist);
    hipLaunchKernelGGL(scan1_kernel, dim3(nb), dim3(256), 0, stream, hist, pre, bsum);
    hipLaunchKernelGGL(scan23_kernel, dim3(nb), dim3(256), 0, stream, pre, bsum, row_off);
    hipLaunchKernelGGL(mid_kernel, dim3(nbn + neb), dim3(256), 0, stream,
                       x, b1a, hrp, hsp, rcv, snd, row_off, cursor, srt, nbn);

    // layer-1 edges + mean + layer-2 GEMM1 (writes hrp2/hsp2)
    hipLaunchKernelGGL(fused_edge_kernel, dim3(nbn), dim3(512), 0, stream,
                       hrp, hsp, srt, row_off, hist, b2a, 0,
                       b1b, hrp2, hsp2,
                       (const float*)nullptr, (const float*)nullptr,
                       (const float*)nullptr, (float*)nullptr, 0);
    // layer-2 edges + mean + dense tail (writes out)
    hipLaunchKernelGGL(fused_edge_kernel, dim3(nbn), dim3(512), 0, stream,
                       hrp2, hsp2, srt, row_off, hist, b2b, 1,
                       (const float*)nullptr, (float*)nullptr, (float*)nullptr,
                       bd1, Wd2, bd2, out, 1);
}

// Round 6
// 681.894 us; speedup vs baseline: 1.0252x; 1.0252x over previous
//
#include <hip/hip_runtime.h>
#include <hip/hip_bf16.h>
#include <cstdint>
#include <cstddef>

#define NN 50000
#define NE 800000

typedef __bf16 bf16x8 __attribute__((ext_vector_type(8)));
typedef float  f32x4  __attribute__((ext_vector_type(4)));

// Pre-split, pre-transposed weights (hi/lo bf16 planes).
// W1t: [n][k] n<64,k<256 ; W2t: [n][k] n<128,k<64 ; Wd1t: [n][k] n<64,k<128.
__device__ __bf16 g_w1h[2][64 * 256];
__device__ __bf16 g_w1l[2][64 * 256];
__device__ __bf16 g_w2h[2][128 * 64];
__device__ __bf16 g_w2l[2][128 * 64];
__device__ __bf16 g_wd1h[64 * 128];
__device__ __bf16 g_wd1l[64 * 128];

__device__ __forceinline__ void split1(float v, __bf16& h, __bf16& l) {
    h = (__bf16)v;
    l = (__bf16)(v - (float)h);
}

// ---------------------------------------------------------------------------
// pre_kernel: blocks [0,224) split weights; blocks [224,224+3125) histogram
// ---------------------------------------------------------------------------
__global__ __launch_bounds__(256) void pre_kernel(
    const float* __restrict__ W1a, const float* __restrict__ W2a,
    const float* __restrict__ W1b, const float* __restrict__ W2b,
    const float* __restrict__ Wd1,
    const int* __restrict__ rcv, uint32_t* __restrict__ hist)
{
    const int b = blockIdx.x, t = threadIdx.x;
    if (b < 224) {
        int tid = b * 256 + t;
        if (tid < 16384) {                 // W1a [256][64] -> [64][256]
            int k = tid >> 6, n = tid & 63;
            __bf16 h, l; split1(W1a[tid], h, l);
            g_w1h[0][n * 256 + k] = h; g_w1l[0][n * 256 + k] = l;
        } else if (tid < 24576) {          // W2a [64][128] -> [128][64]
            int i = tid - 16384; int k = i >> 7, n = i & 127;
            __bf16 h, l; split1(W2a[i], h, l);
            g_w2h[0][n * 64 + k] = h; g_w2l[0][n * 64 + k] = l;
        } else if (tid < 40960) {          // W1b
            int i = tid - 24576; int k = i >> 6, n = i & 63;
            __bf16 h, l; split1(W1b[i], h, l);
            g_w1h[1][n * 256 + k] = h; g_w1l[1][n * 256 + k] = l;
        } else if (tid < 49152) {          // W2b
            int i = tid - 40960; int k = i >> 7, n = i & 127;
            __bf16 h, l; split1(W2b[i], h, l);
            g_w2h[1][n * 64 + k] = h; g_w2l[1][n * 64 + k] = l;
        } else if (tid < 57344) {          // Wd1 [128][64] -> [64][128]
            int i = tid - 49152; int k = i >> 6, n = i & 63;
            __bf16 h, l; split1(Wd1[i], h, l);
            g_wd1h[n * 128 + k] = h; g_wd1l[n * 128 + k] = l;
        }
    } else {
        int e = (b - 224) * 256 + t;
        if (e < NE) atomicAdd(hist + rcv[e], 1u);
    }
}

// ---------------------------------------------------------------------------
// counting-sort scan (exact counts)
// ---------------------------------------------------------------------------
__global__ void scan1_kernel(const uint32_t* __restrict__ hist,
                             uint32_t* __restrict__ pre, uint32_t* __restrict__ bsum) {
    __shared__ uint32_t s[256];
    int t = threadIdx.x;
    int i = blockIdx.x * 256 + t;
    uint32_t v = (i < NN) ? hist[i] : 0u;
    s[t] = v; __syncthreads();
    #pragma unroll
    for (int off = 1; off < 256; off <<= 1) {
        uint32_t tv = (t >= off) ? s[t - off] : 0u;
        __syncthreads();
        s[t] += tv; __syncthreads();
    }
    if (i < NN) pre[i] = s[t] - v;
    if (t == 255) bsum[blockIdx.x] = s[255];
}

__global__ void scan23_kernel(const uint32_t* __restrict__ pre,
                              const uint32_t* __restrict__ bsum,
                              uint32_t* __restrict__ row_off) {
    __shared__ uint32_t s[256];
    const int b = blockIdx.x, t = threadIdx.x;
    uint32_t v = (t < b) ? bsum[t] : 0u;     // b <= 195 < 256
    s[t] = v; __syncthreads();
    #pragma unroll
    for (int off = 128; off > 0; off >>= 1) {
        if (t < off) s[t] += s[t + off];
        __syncthreads();
    }
    const uint32_t base = s[0];
    int i = b * 256 + t;
    if (i < NN) row_off[i] = pre[i] + base;
    if (i == 0) row_off[NN] = NE;
}

// ---------------------------------------------------------------------------
// node_w1_body: layer-0 per-node half-products of GEMM1 (global src).
//   hrp[n] = src[n] @ W1_top + b1 ; hsp[n] = src[n] @ W1_bot
// ---------------------------------------------------------------------------
__device__ __forceinline__ void node_w1_body(
    const float* __restrict__ src, const float* __restrict__ b1,
    float* __restrict__ hrp, float* __restrict__ hsp, int blk)
{
    __shared__ __align__(16) __bf16 sAh[64 * 136];
    __shared__ __align__(16) __bf16 sAl[64 * 136];
    const int t = threadIdx.x;
    const int w = t >> 6, lane = t & 63, quad = lane >> 4, l16 = lane & 15;
    const int node0 = blk * 64;

    {
        const int r = t >> 2, kq = (t & 3) * 32;
        const int node = node0 + r;
        f32x4 v[8];
        if (node < NN) {
            const float* p = src + (size_t)node * 128 + kq;
            #pragma unroll
            for (int i = 0; i < 8; ++i) v[i] = *(const f32x4*)(p + 4 * i);
        } else {
            #pragma unroll
            for (int i = 0; i < 8; ++i) v[i] = (f32x4){0.f, 0.f, 0.f, 0.f};
        }
        bf16x8 hb[4], lb[4];
        #pragma unroll
        for (int i = 0; i < 8; ++i) {
            #pragma unroll
            for (int j = 0; j < 4; ++j) {
                __bf16 h, l; split1(v[i][j], h, l);
                hb[i >> 1][(i & 1) * 4 + j] = h;
                lb[i >> 1][(i & 1) * 4 + j] = l;
            }
        }
        __bf16* dh = sAh + r * 136 + kq;
        __bf16* dl = sAl + r * 136 + kq;
        #pragma unroll
        for (int i = 0; i < 4; ++i) {
            *(bf16x8*)(dh + 8 * i) = hb[i];
            *(bf16x8*)(dl + 8 * i) = lb[i];
        }
    }
    __syncthreads();

    const int n = 16 * w + l16;
    const __bf16* w1hp = g_w1h[0] + n * 256;
    const __bf16* w1lp = g_w1l[0] + n * 256;
    f32x4 acc[4][2] = {};
    #pragma unroll
    for (int kq = 0; kq < 4; ++kq) {
        const int k0 = kq * 32 + quad * 8;
        bf16x8 bh0 = *(const bf16x8*)(w1hp + k0);
        bf16x8 bl0 = *(const bf16x8*)(w1lp + k0);
        bf16x8 bh1 = *(const bf16x8*)(w1hp + 128 + k0);
        bf16x8 bl1 = *(const bf16x8*)(w1lp + 128 + k0);
        #pragma unroll
        for (int st = 0; st < 4; ++st) {
            bf16x8 ah = *(const bf16x8*)(sAh + (16 * st + l16) * 136 + k0);
            bf16x8 al = *(const bf16x8*)(sAl + (16 * st + l16) * 136 + k0);
            acc[st][0] = __builtin_amdgcn_mfma_f32_16x16x32_bf16(ah, bh0, acc[st][0], 0, 0, 0);
            acc[st][0] = __builtin_amdgcn_mfma_f32_16x16x32_bf16(al, bh0, acc[st][0], 0, 0, 0);
            acc[st][0] = __builtin_amdgcn_mfma_f32_16x16x32_bf16(ah, bl0, acc[st][0], 0, 0, 0);
            acc[st][1] = __builtin_amdgcn_mfma_f32_16x16x32_bf16(ah, bh1, acc[st][1], 0, 0, 0);
            acc[st][1] = __builtin_amdgcn_mfma_f32_16x16x32_bf16(al, bh1, acc[st][1], 0, 0, 0);
            acc[st][1] = __builtin_amdgcn_mfma_f32_16x16x32_bf16(ah, bl1, acc[st][1], 0, 0, 0);
        }
    }

    const float b1v = b1[n];
    #pragma unroll
    for (int st = 0; st < 4; ++st) {
        #pragma unroll
        for (int r = 0; r < 4; ++r) {
            const int node = node0 + 16 * st + quad * 4 + r;
            if (node < NN) {
                hrp[(size_t)node * 64 + n] = acc[st][0][r] + b1v;
                hsp[(size_t)node * 64 + n] = acc[st][1][r];
            }
        }
    }
}

// ---------------------------------------------------------------------------
// mid_kernel: blocks [0,nbn) = node_w1 layer-0; rest = rank-scatter.
// ---------------------------------------------------------------------------
__global__ __launch_bounds__(256) void mid_kernel(
    const float* __restrict__ x, const float* __restrict__ b1a,
    float* __restrict__ hrp, float* __restrict__ hsp,
    const int* __restrict__ rcv, const int* __restrict__ snd,
    const uint32_t* __restrict__ row_off, uint32_t* __restrict__ cursor,
    int2* __restrict__ srt, int nbn)
{
    if ((int)blockIdx.x < nbn) {
        node_w1_body(x, b1a, hrp, hsp, blockIdx.x);
    } else {
        int e = (blockIdx.x - nbn) * 256 + threadIdx.x;
        if (e < NE) {
            int r = rcv[e];
            uint32_t k = atomicAdd(cursor + r, 1u);
            srt[row_off[r] + k] = make_int2(r, snd[e]);
        }
    }
}

// ---------------------------------------------------------------------------
// fused_edge_kernel v3: NODE-CENTRIC, 512 threads (8 waves), ONE strip/wave.
// Block owns 64 receivers + their sorted edge range. Segment sums in a
// 64x128 f32 LDS accumulator -> zero global atomics. One 16-edge strip per
// wave per iteration (8 waves x 16 = 128 edges/iter): halves the live set
// vs r5's two-strip version so the (512,4) 128-VGPR cap holds WITHOUT spill
// (r5 spilled: WRITE 186MB / FETCH 463MB were scratch traffic).
// Branch-free suffix-sum epilogue, <=4 predicated ds_adds per ct.
// LDS 67.8KB -> 2 blocks (16 waves)/CU when VGPR<=128.
// Fused per block: mean via hist, then
//   tail_mode=0: layer-2 GEMM1 -> hrpO/hspO   tail_mode=1: dense tail -> outp
// GEMM phase uses all 8 waves: waves 0-3 node-strips {0,1}, waves 4-7 {2,3}.
// ---------------------------------------------------------------------------
__global__ __launch_bounds__(512, 4) void fused_edge_kernel(
    const float* __restrict__ hrpI, const float* __restrict__ hspI,
    const int2* __restrict__ srt, const uint32_t* __restrict__ row_off,
    const uint32_t* __restrict__ hist,
    const float* __restrict__ b2, int layer,
    const float* __restrict__ b1n, float* __restrict__ hrpO, float* __restrict__ hspO,
    const float* __restrict__ bd1, const float* __restrict__ Wd2,
    const float* __restrict__ bd2, float* __restrict__ outp,
    int tail_mode)
{
    __shared__ __align__(16) float sAcc[64][128];              // 32768 B
    __shared__ __align__(16) char  sBuf[64 * 136 * 2 * 2];     // 34816 B
    __shared__ float sOut[64];

    __bf16* sWh = (__bf16*)sBuf;            // [128*64] during edge phase
    __bf16* sWl = sWh + 128 * 64;
    __bf16* sAh = (__bf16*)sBuf;            // [64*136] during GEMM phase
    __bf16* sAl = sAh + 64 * 136;

    const int t = threadIdx.x;
    const int w = t >> 6, lane = t & 63, quad = lane >> 4, l16 = lane & 15;
    const int node0 = blockIdx.x * 64;

    // ---- zero sAcc (8192 f32 / 512 threads) --------------------------------
    #pragma unroll
    for (int i = 0; i < 4; ++i)
        *(f32x4*)(&sAcc[0][0] + t * 4 + i * 2048) = (f32x4){0.f, 0.f, 0.f, 0.f};
    if (t < 64) sOut[t] = 0.f;

    // ---- stage W2 planes, swizzled (chunk c of row r at slot c^(r&7)) ------
    {
        const int r = t >> 2, part = t & 3;
        const __bf16* sh = g_w2h[layer] + r * 64;
        const __bf16* sl = g_w2l[layer] + r * 64;
        __bf16* dh = sWh + r * 64;
        __bf16* dl = sWl + r * 64;
        const int rs = r & 7;
        #pragma unroll
        for (int i = 0; i < 2; ++i) {
            const int c = part * 2 + i;
            const int cs = c ^ rs;
            *(bf16x8*)(dh + cs * 8) = *(const bf16x8*)(sh + 8 * c);
            *(bf16x8*)(dl + cs * 8) = *(const bf16x8*)(sl + 8 * c);
        }
    }

    float b2v[8];
    #pragma unroll
    for (int ct = 0; ct < 8; ++ct) b2v[ct] = b2[16 * ct + l16];

    const int e0 = (int)row_off[node0];
    const int e1 = (int)row_off[(node0 + 64 < NN) ? (node0 + 64) : NN];

    __syncthreads();   // sAcc zeroed + weights staged

    // ---- edge loop: wave w handles ONE 16-edge strip/iter, 8 waves->128 ----
    for (int base = e0 + w * 16; base < e1; base += 128) {
        const int iA = base + l16;
        const bool vA = iA < e1;
        const int2 rsA = srt[vA ? iA : e1 - 1];
        const int rlA = vA ? (rsA.x - node0) : -1;   // local receiver or -1

        const float* hpA = hrpI + (size_t)rsA.x * 64 + quad * 8;
        const float* spA = hspI + (size_t)rsA.y * 64 + quad * 8;

        f32x4 ga0[4], gb0[4];
        ga0[0] = *(const f32x4*)(hpA);      ga0[1] = *(const f32x4*)(hpA + 4);
        ga0[2] = *(const f32x4*)(hpA + 32); ga0[3] = *(const f32x4*)(hpA + 36);
        gb0[0] = *(const f32x4*)(spA);      gb0[1] = *(const f32x4*)(spA + 4);
        gb0[2] = *(const f32x4*)(spA + 32); gb0[3] = *(const f32x4*)(spA + 36);

        // ---- per-quad receivers + branch-free run structure ----------------
        const int rA0 = __shfl(rlA, quad * 4 + 0, 16);
        const int rA1 = __shfl(rlA, quad * 4 + 1, 16);
        const int rA2 = __shfl(rlA, quad * 4 + 2, 16);
        const int rA3 = __shfl(rlA, quad * 4 + 3, 16);

        const float cA01 = (rA1 == rA0) ? 1.f : 0.f;
        const float cA12 = (rA2 == rA1) ? 1.f : 0.f;
        const float cA23 = (rA3 == rA2) ? 1.f : 0.f;
        const bool hA0 = (rA0 >= 0);
        const bool hA1 = (rA1 != rA0) && (rA1 >= 0);
        const bool hA2 = (rA2 != rA1) && (rA2 >= 0);
        const bool hA3 = (rA3 != rA2) && (rA3 >= 0);
        const float mA0 = (rA0 >= 0) ? 1.f : 0.f;
        const float mA1 = (rA1 >= 0) ? 1.f : 0.f;
        const float mA2 = (rA2 >= 0) ? 1.f : 0.f;
        const float mA3 = (rA3 >= 0) ? 1.f : 0.f;

        // ---- pack A-fragments: h = relu(hrp+hsp), split hi/lo --------------
        bf16x8 ahA[2], alA[2];
        #pragma unroll
        for (int s = 0; s < 2; ++s) {
            #pragma unroll
            for (int hh = 0; hh < 2; ++hh) {
                f32x4 av = ga0[s * 2 + hh], bv = gb0[s * 2 + hh];
                #pragma unroll
                for (int j = 0; j < 4; ++j) {
                    float fA = fmaxf(av[j] + bv[j], 0.f);
                    __bf16 h, l;
                    split1(fA, h, l); ahA[s][hh * 4 + j] = h; alA[s][hh * 4 + j] = l;
                }
            }
        }

        #pragma unroll
        for (int ct = 0; ct < 8; ++ct) {
            const int r = 16 * ct + l16;
            const int rs = r & 7;
            f32x4 accA = {};
            __builtin_amdgcn_s_setprio(1);
            #pragma unroll
            for (int s = 0; s < 2; ++s) {
                const int cs = (s * 4 + quad) ^ rs;
                bf16x8 bh = *(const bf16x8*)(sWh + r * 64 + cs * 8);
                bf16x8 bl = *(const bf16x8*)(sWl + r * 64 + cs * 8);
                accA = __builtin_amdgcn_mfma_f32_16x16x32_bf16(ahA[s], bh, accA, 0, 0, 0);
                accA = __builtin_amdgcn_mfma_f32_16x16x32_bf16(alA[s], bh, accA, 0, 0, 0);
                accA = __builtin_amdgcn_mfma_f32_16x16x32_bf16(ahA[s], bl, accA, 0, 0, 0);
            }
            __builtin_amdgcn_s_setprio(0);
            const float bv = b2v[ct];
            const float v0 = fmaxf(accA[0] + bv, 0.f) * mA0;
            const float v1 = fmaxf(accA[1] + bv, 0.f) * mA1;
            const float v2 = fmaxf(accA[2] + bv, 0.f) * mA2;
            const float v3 = fmaxf(accA[3] + bv, 0.f) * mA3;
            const float t3 = v3;
            const float t2 = fmaf(cA23, t3, v2);
            const float t1 = fmaf(cA12, t2, v1);
            const float t0 = fmaf(cA01, t1, v0);
            if (hA0) atomicAdd(&sAcc[rA0][r], t0);
            if (hA1) atomicAdd(&sAcc[rA1][r], t1);
            if (hA2) atomicAdd(&sAcc[rA2][r], t2);
            if (hA3) atomicAdd(&sAcc[rA3][r], t3);
        }
    }

    __syncthreads();   // sAcc complete; sWh/sWl dead -> reuse as sAh/sAl

    // ---- stage mean(sAcc) -> sAh/sAl (512 threads: 16 f32 each) ------------
    {
        const int r = t >> 3, kq = (t & 7) * 16;
        const int node = node0 + r;
        float inv = 0.f;
        if (node < NN) {
            const uint32_t c = hist[node];
            inv = (c > 0u) ? 1.0f / (float)c : 0.f;
        }
        f32x4 v[4];
        #pragma unroll
        for (int i = 0; i < 4; ++i)
            v[i] = *(const f32x4*)(&sAcc[r][kq + 4 * i]) * inv;
        bf16x8 hb[2], lb[2];
        #pragma unroll
        for (int i = 0; i < 4; ++i) {
            #pragma unroll
            for (int j = 0; j < 4; ++j) {
                __bf16 h, l; split1(v[i][j], h, l);
                hb[i >> 1][(i & 1) * 4 + j] = h;
                lb[i >> 1][(i & 1) * 4 + j] = l;
            }
        }
        __bf16* dh = sAh + r * 136 + kq;
        __bf16* dl = sAl + r * 136 + kq;
        *(bf16x8*)(dh) = hb[0];  *(bf16x8*)(dh + 8) = hb[1];
        *(bf16x8*)(dl) = lb[0];  *(bf16x8*)(dl + 8) = lb[1];
    }
    __syncthreads();

    // ---- GEMM phase: all 8 waves. wave w: cols 16*(w&3)+l16, strips sb,sb+1
    const int wh = w & 3;
    const int sb = (w >> 2) * 2;
    const int n = 16 * wh + l16;

    if (!tail_mode) {
        const __bf16* w1hp = g_w1h[1] + n * 256;
        const __bf16* w1lp = g_w1l[1] + n * 256;
        f32x4 acc[2][2] = {};
        #pragma unroll
        for (int kq = 0; kq < 4; ++kq) {
            const int k0 = kq * 32 + quad * 8;
            bf16x8 bh0 = *(const bf16x8*)(w1hp + k0);
            bf16x8 bl0 = *(const bf16x8*)(w1lp + k0);
            bf16x8 bh1 = *(const bf16x8*)(w1hp + 128 + k0);
            bf16x8 bl1 = *(const bf16x8*)(w1lp + 128 + k0);
            #pragma unroll
            for (int sl = 0; sl < 2; ++sl) {
                const int st = sb + sl;
                bf16x8 ah = *(const bf16x8*)(sAh + (16 * st + l16) * 136 + k0);
                bf16x8 al = *(const bf16x8*)(sAl + (16 * st + l16) * 136 + k0);
                acc[sl][0] = __builtin_amdgcn_mfma_f32_16x16x32_bf16(ah, bh0, acc[sl][0], 0, 0, 0);
                acc[sl][0] = __builtin_amdgcn_mfma_f32_16x16x32_bf16(al, bh0, acc[sl][0], 0, 0, 0);
                acc[sl][0] = __builtin_amdgcn_mfma_f32_16x16x32_bf16(ah, bl0, acc[sl][0], 0, 0, 0);
                acc[sl][1] = __builtin_amdgcn_mfma_f32_16x16x32_bf16(ah, bh1, acc[sl][1], 0, 0, 0);
                acc[sl][1] = __builtin_amdgcn_mfma_f32_16x16x32_bf16(al, bh1, acc[sl][1], 0, 0, 0);
                acc[sl][1] = __builtin_amdgcn_mfma_f32_16x16x32_bf16(ah, bl1, acc[sl][1], 0, 0, 0);
            }
        }
        const float b1v = b1n[n];
        #pragma unroll
        for (int sl = 0; sl < 2; ++sl) {
            const int st = sb + sl;
            #pragma unroll
            for (int r2 = 0; r2 < 4; ++r2) {
                const int node = node0 + 16 * st + quad * 4 + r2;
                if (node < NN) {
                    hrpO[(size_t)node * 64 + n] = acc[sl][0][r2] + b1v;
                    hspO[(size_t)node * 64 + n] = acc[sl][1][r2];
                }
            }
        }
    } else {
        const __bf16* bhp = g_wd1h + n * 128;
        const __bf16* blp = g_wd1l + n * 128;
        f32x4 acc[2] = {};
        #pragma unroll
        for (int kq = 0; kq < 4; ++kq) {
            const int k0 = kq * 32 + quad * 8;
            bf16x8 bh = *(const bf16x8*)(bhp + k0);
            bf16x8 bl = *(const bf16x8*)(blp + k0);
            #pragma unroll
            for (int sl = 0; sl < 2; ++sl) {
                const int st = sb + sl;
                bf16x8 ah = *(const bf16x8*)(sAh + (16 * st + l16) * 136 + k0);
                bf16x8 al = *(const bf16x8*)(sAl + (16 * st + l16) * 136 + k0);
                acc[sl] = __builtin_amdgcn_mfma_f32_16x16x32_bf16(ah, bh, acc[sl], 0, 0, 0);
                acc[sl] = __builtin_amdgcn_mfma_f32_16x16x32_bf16(al, bh, acc[sl], 0, 0, 0);
                acc[sl] = __builtin_amdgcn_mfma_f32_16x16x32_bf16(ah, bl, acc[sl], 0, 0, 0);
            }
        }
        const float bd1v = bd1[n];
        const float wd2v = Wd2[n];
        #pragma unroll
        for (int sl = 0; sl < 2; ++sl) {
            const int st = sb + sl;
            #pragma unroll
            for (int r2 = 0; r2 < 4; ++r2) {
                float p = fmaxf(acc[sl][r2] + bd1v, 0.f) * wd2v;
                p += __shfl_xor(p, 1, 16);
                p += __shfl_xor(p, 2, 16);
                p += __shfl_xor(p, 4, 16);
                p += __shfl_xor(p, 8, 16);
                if (l16 == 0) atomicAdd(&sOut[16 * st + quad * 4 + r2], p);
            }
        }
        __syncthreads();
        if (t < 64) {
            const int node = node0 + t;
            if (node < NN) outp[node] = sOut[t] + bd2[0];
        }
    }
}

// ---------------------------------------------------------------------------
extern "C" void kernel_launch(void* const* d_in, const int* in_sizes, int n_in,
                              void* d_out, int out_size, void* d_ws, size_t ws_size,
                              hipStream_t stream) {
    const float* x   = (const float*)d_in[0];
    const int*   snd = (const int*)  d_in[1];
    const int*   rcv = (const int*)  d_in[2];
    const float* W1a = (const float*)d_in[3];
    const float* b1a = (const float*)d_in[4];
    const float* W2a = (const float*)d_in[5];
    const float* b2a = (const float*)d_in[6];
    const float* W1b = (const float*)d_in[7];
    const float* b1b = (const float*)d_in[8];
    const float* W2b = (const float*)d_in[9];
    const float* b2b = (const float*)d_in[10];
    const float* Wd1 = (const float*)d_in[11];
    const float* bd1 = (const float*)d_in[12];
    const float* Wd2 = (const float*)d_in[13];
    const float* bd2 = (const float*)d_in[14];
    float* out = (float*)d_out;

    // ws layout: hist [NN] | cursor [NN] | row_off [NN+1] | pre [NN] |
    //            bsum [256] | pad [1] | srt [NE int2] | hrp | hsp | hrp2 | hsp2
    uint32_t* hist    = (uint32_t*)d_ws;
    uint32_t* cursor  = hist + NN;
    uint32_t* row_off = cursor + NN;
    uint32_t* pre     = row_off + (NN + 1);
    uint32_t* bsum    = pre + NN;
    int2*     srt     = (int2*)(bsum + 256 + 1);   // +1 pad -> 8B aligned
    float*    hrp     = (float*)(srt + NE);
    float*    hsp     = hrp  + (size_t)NN * 64;
    float*    hrp2    = hsp  + (size_t)NN * 64;
    float*    hsp2    = hrp2 + (size_t)NN * 64;

    hipMemsetAsync(hist, 0, 2 * NN * sizeof(uint32_t), stream);   // hist+cursor

    const int nb  = (NN + 255) / 256;   // 196
    const int nbn = (NN + 63) / 64;     // 782
    const int neb = (NE + 255) / 256;   // 3125

    hipLaunchKernelGGL(pre_kernel, dim3(224 + neb), dim3(256), 0, stream,
                       W1a, W2a, W1b, W2b, Wd1, rcv, hist);
    hipLaunchKernelGGL(scan1_kernel, dim3(nb), dim3(256), 0, stream, hist, pre, bsum);
    hipLaunchKernelGGL(scan23_kernel, dim3(nb), dim3(256), 0, stream, pre, bsum, row_off);
    hipLaunchKernelGGL(mid_kernel, dim3(nbn + neb), dim3(256), 0, stream,
                       x, b1a, hrp, hsp, rcv, snd, row_off, cursor, srt, nbn);

    // layer-1 edges + mean + layer-2 GEMM1 (writes hrp2/hsp2)
    hipLaunchKernelGGL(fused_edge_kernel, dim3(nbn), dim3(512), 0, stream,
                       hrp, hsp, srt, row_off, hist, b2a, 0,
                       b1b, hrp2, hsp2,
                       (const float*)nullptr, (const float*)nullptr,
                       (const float*)nullptr, (float*)nullptr, 0);
    // layer-2 edges + mean + dense tail (writes out)
    hipLaunchKernelGGL(fused_edge_kernel, dim3(nbn), dim3(512), 0, stream,
                       hrp2, hsp2, srt, row_off, hist, b2b, 1,
                       (const float*)nullptr, (float*)nullptr, (float*)nullptr,
                       bd1, Wd2, bd2, out, 1);
}